// Round 3
// baseline (399.658 us; speedup 1.0000x reference)
//
#include <hip/hip_runtime.h>

#define NTOK 32768      // 8*4096 tokens
#define HDIM 1024
#define NEXP 64
#define TK   8
#define NB   8
#define SEQ  4096

#define TPB   128               // tokens per block (8 tiles of 16, contiguous 512KB stream)
#define TT    16                // tokens per tile = 64KB contiguous DRAM
#define NTILE (TPB / TT)        // 8
#define NTHR  256               // 4 waves; wave w = expert fragment wn (16 experts each)
#define NBLK  (NTOK / TPB)      // 256 blocks = 1 per CU

#define ABUF  65536             // A tile buffer: 16 rows x 1024 f32

typedef __attribute__((ext_vector_type(8))) short bf16x8;   // 8 bf16 = 4 VGPRs
typedef __attribute__((ext_vector_type(4))) float f32x4;

union BF8 { bf16x8 v; unsigned u[4]; };

__device__ inline unsigned f2bf(float x) {          // RTN-even fp32 -> bf16 bits
    unsigned u = __float_as_uint(x);
    return (u + 0x7FFFu + ((u >> 16) & 1u)) >> 16;
}

__device__ inline void split4(float4 v, unsigned* hp, unsigned* lp) {
    unsigned h0 = f2bf(v.x), h1 = f2bf(v.y), h2 = f2bf(v.z), h3 = f2bf(v.w);
    unsigned l0 = f2bf(v.x - __uint_as_float(h0 << 16));
    unsigned l1 = f2bf(v.y - __uint_as_float(h1 << 16));
    unsigned l2 = f2bf(v.z - __uint_as_float(h2 << 16));
    unsigned l3 = f2bf(v.w - __uint_as_float(h3 << 16));
    hp[0] = h0 | (h1 << 16); hp[1] = h2 | (h3 << 16);
    lp[0] = l0 | (l1 << 16); lp[1] = l2 | (l3 << 16);
}

// async global->LDS, 16B/lane; LDS dest = wave-uniform base + lane*16
__device__ __forceinline__ void gl16(const void* g, void* l) {
    __builtin_amdgcn_global_load_lds(
        (const __attribute__((address_space(1))) void*)g,
        (__attribute__((address_space(3))) void*)l, 16, 0, 0);
}

// One-time: split W into Dekker hi/lo bf16 AND pre-arrange in MFMA B-fragment
// order: slot(c,s,n) holds 64 lanes x 16B; lane l -> B[e=n*16+(l&15)]
// [k=c*64+s*32+(l>>4)*8 .. +8].
__global__ void wsplit(const float* __restrict__ w,
                       unsigned short* __restrict__ whi,
                       unsigned short* __restrict__ wlo)
{
    int T = blockIdx.x * 256 + threadIdx.x;     // 8192 threads = 128 slots x 64
    int slot = T >> 6, l = T & 63;
    int c = slot >> 3, s = (slot >> 2) & 1, n = slot & 3;
    int e = n * 16 + (l & 15);
    int k = c * 64 + s * 32 + (l >> 4) * 8;
    const float* src = w + (size_t)e * HDIM + k;
    float4 v0 = *(const float4*)(src);
    float4 v1 = *(const float4*)(src + 4);
    unsigned hp[4], lp[4];
    split4(v0, &hp[0], &lp[0]);
    split4(v1, &hp[2], &lp[2]);
    ((uint4*)whi)[T] = make_uint4(hp[0], hp[1], hp[2], hp[3]);
    ((uint4*)wlo)[T] = make_uint4(lp[0], lp[1], lp[2], lp[3]);
}

// R3: full-K 16-token tiles. R0-R2 all ran at dur = FETCH/~780GB/s: K-chunked
// staging reads each 4KB row in 16 scattered 256B slivers -> DRAM page-hit
// rate ~0 -> HBM crippled to 12% of peak. Now each stage is ONE contiguous
// 64KB block (16 consecutive rows, full K), double-buffered at tile level;
// each block streams 512KB sequentially. A is still read exactly once.
// B comes direct from the L2-resident frag-ordered ws (R2 proved this free).
// 1 block/CU (136KB LDS) by design: producer is gl16 DMA, consumer MFMA+VALU.
__global__ __launch_bounds__(NTHR, 1) void moe_main(
    const float* __restrict__ hidden,           // [NTOK][HDIM]
    const unsigned short* __restrict__ w2hi,    // frag-ordered bf16 hi
    const unsigned short* __restrict__ w2lo,    // frag-ordered bf16 lo
    float* __restrict__ out,                    // idx | w | aux | counts
    float* __restrict__ ws)                     // C[8][64] | Sm[8][64]
{
    __shared__ __align__(16) unsigned char smem[2 * ABUF];  // A tile dbuf
    __shared__ float sLog[TT * 66];                         // logits, pad 66
    __shared__ float smSum[NEXP];
    __shared__ int   hist[NEXP];

    const int tid   = threadIdx.x;
    const int w     = tid >> 6;         // 0..3 = expert fragment wn
    const int l     = tid & 63;
    const int m     = l & 15;
    const int q     = l >> 4;
    const int wbase = tid & 192;        // wave-uniform slot base
    const size_t t0 = (size_t)blockIdx.x * TPB;

    if (tid < NEXP) { smSum[tid] = 0.f; hist[tid] = 0; }

    // prologue: stage tile 0 (16 rows x 4KB, XOR-swizzled cols within 256B groups)
    {
        const float* base = hidden + t0 * HDIM;
#pragma unroll
        for (int i = 0; i < 16; ++i) {
            int L = i * NTHR + tid;                 // 16B-slot 0..4095
            int r = L >> 8;                         // row 0..15 (wave-uniform)
            int u = L & 255;                        // slot within row
            int sc = (u & 0xF0) | ((u & 15) ^ r);   // inverse swizzle on source
            gl16(base + (size_t)r * HDIM + sc * 4,
                 smem + (size_t)(i * NTHR + wbase) * 16);
        }
    }
    __syncthreads();

    float mxKeep = 0.f;     // per-lane carry of token (w*4 + (l&3))'s max

    for (int tile = 0; tile < NTILE; ++tile) {
        const unsigned char* Ab = smem + (tile & 1) * ABUF;

        // prefetch tile+1 (contiguous 64KB) into the other buffer; drained by
        // the vmcnt(0) folded into barrier A below (overlap = whole K-loop)
        if (tile + 1 < NTILE) {
            unsigned char* nb = smem + ((tile + 1) & 1) * ABUF;
            const float* base = hidden + (t0 + (size_t)(tile + 1) * TT) * HDIM;
#pragma unroll
            for (int i = 0; i < 16; ++i) {
                int L = i * NTHR + tid;
                int r = L >> 8;
                int u = L & 255;
                int sc = (u & 0xF0) | ((u & 15) ^ r);
                gl16(base + (size_t)r * HDIM + sc * 4,
                     nb + (size_t)(i * NTHR + wbase) * 16);
            }
        }

        // K-loop: 32 K32-steps; wave tile M=16 x N=16 (experts w*16..w*16+16)
        f32x4 acc = (f32x4)0.f;
#pragma unroll
        for (int s = 0; s < 32; ++s) {
            // B fragments direct from L2-resident frag-ordered workspace
            size_t boff = ((size_t)((s >> 1) * 8 + (s & 1) * 4 + w) * 64 + l) * 8;
            bf16x8 bh = *(const bf16x8*)(w2hi + boff);
            bf16x8 bl = *(const bf16x8*)(w2lo + boff);
            // A fragment from swizzled LDS: row m, logical slots s*8+q*2+{0,1}
            int grp = (s >> 1) << 4;
            int p0  = ((s & 1) * 8 + q * 2)     ^ m;
            int p1  = ((s & 1) * 8 + q * 2 + 1) ^ m;
            float4 a0 = *(const float4*)(Ab + ((size_t)(m << 8) + grp + p0) * 16);
            float4 a1 = *(const float4*)(Ab + ((size_t)(m << 8) + grp + p1) * 16);
            BF8 ah, al;
            split4(a0, &ah.u[0], &al.u[0]);
            split4(a1, &ah.u[2], &al.u[2]);
            acc = __builtin_amdgcn_mfma_f32_16x16x32_bf16(ah.v, bh, acc, 0, 0, 0);
            acc = __builtin_amdgcn_mfma_f32_16x16x32_bf16(al.v, bh, acc, 0, 0, 0);
            acc = __builtin_amdgcn_mfma_f32_16x16x32_bf16(ah.v, bl, acc, 0, 0, 0);
        }

        __syncthreads();    // barrier A: K-loop done (all waves), prefetch drained,
                            // and prior tile's phase-2 reads of sLog complete

        // logits -> LDS: token row=(q*4+rr), expert col=w*16+m
#pragma unroll
        for (int rr = 0; rr < 4; ++rr)
            sLog[(q * 4 + rr) * 66 + w * 16 + m] = acc[rr];
        __syncthreads();    // barrier B: sLog visible

        // ---- phase 2a: softmax stats; wave w -> tokens [4w, 4w+4), lane=expert
        float regSm = 0.f;
#pragma unroll
        for (int jj = 0; jj < 4; ++jj) {
            int t = w * 4 + jj;
            float x = sLog[t * 66 + l];
            float mx = x;
#pragma unroll
            for (int off = 32; off; off >>= 1) mx = fmaxf(mx, __shfl_xor(mx, off));
            float p = __expf(x - mx);
            float sd = p;
#pragma unroll
            for (int off = 32; off; off >>= 1) sd += __shfl_xor(sd, off);
            regSm += p / sd;
            if (jj == (l & 3)) mxKeep = mx;     // keep for 2b (no LDS roundtrip)
        }
        atomicAdd(&smSum[l], regSm);

        // ---- phase 2b: top-8; lanes 0..3 of wave w -> token w*4 + l ----
        // no trailing barrier: slow 2b hides under next tile's K-loop
        if (l < 4) {
            const int   tl = w * 4 + l;
            const float mx = mxKeep;
            unsigned long long s8[TK];
#pragma unroll
            for (int j = 0; j < TK; ++j) s8[j] = 0ull;
            for (int e = 0; e < NEXP; ++e) {
                float x = sLog[tl * 66 + e];
                unsigned u = __float_as_uint(x);
                unsigned k32 = (u & 0x80000000u) ? ~u : (u | 0x80000000u);
                unsigned long long key = ((unsigned long long)k32 << 6)
                                       | (unsigned long long)(63 - e);
                if (key > s8[TK - 1]) {
#pragma unroll
                    for (int j = 0; j < TK; ++j) {
                        unsigned long long hi = s8[j] > key ? s8[j] : key;
                        key = s8[j] > key ? key : s8[j];
                        s8[j] = hi;
                    }
                }
            }
            float ev[TK]; int ei[TK]; float sum = 0.f;
#pragma unroll
            for (int j = 0; j < TK; ++j) {
                unsigned k32 = (unsigned)(s8[j] >> 6);
                unsigned u = (k32 >> 31) ? (k32 ^ 0x80000000u) : ~k32;
                ev[j] = __expf(__uint_as_float(u) - mx);
                sum += ev[j];
                ei[j] = 63 - (int)(s8[j] & 63ull);
            }
            size_t t = t0 + (size_t)tile * TT + tl;
            float4 i0 = make_float4((float)ei[0], (float)ei[1], (float)ei[2], (float)ei[3]);
            float4 i1 = make_float4((float)ei[4], (float)ei[5], (float)ei[6], (float)ei[7]);
            *(float4*)(out + t * TK)     = i0;
            *(float4*)(out + t * TK + 4) = i1;
            float rs = 1.f / (sum + 1e-20f);
            float4 w0 = make_float4(ev[0] * rs, ev[1] * rs, ev[2] * rs, ev[3] * rs);
            float4 w1 = make_float4(ev[4] * rs, ev[5] * rs, ev[6] * rs, ev[7] * rs);
            *(float4*)(out + (size_t)NTOK * TK + t * TK)     = w0;
            *(float4*)(out + (size_t)NTOK * TK + t * TK + 4) = w1;
#pragma unroll
            for (int j = 0; j < TK; ++j) atomicAdd(&hist[ei[j]], 1);
        }
    }
    __syncthreads();

    if (tid < NEXP) {
        int b = blockIdx.x >> 5;            // 32 blocks per batch element
        atomicAdd(&ws[b * NEXP + tid], (float)hist[tid]);
        atomicAdd(&ws[NB * NEXP + b * NEXP + tid], smSum[tid]);
    }
}

__global__ void moe_finalize(const float* __restrict__ ws, float* __restrict__ out)
{
    int e = threadIdx.x;   // 64 threads
    float cnt = 0.f, accv = 0.f;
#pragma unroll
    for (int b = 0; b < NB; ++b) {
        float c  = ws[b * NEXP + e];
        float sm = ws[NB * NEXP + b * NEXP + e];
        cnt += c;
        accv += c * sm;
    }
    out[(size_t)NTOK * TK * 2 + 1 + e] = cnt;   // expert_counts (as float)
#pragma unroll
    for (int off = 32; off; off >>= 1) accv += __shfl_xor(accv, off);
    if (e == 0) {
        float aux = 0.01f * accv * ((float)NEXP / ((float)SEQ * (float)TK))
                    / (float)SEQ / (float)NB;
        out[(size_t)NTOK * TK * 2] = aux;
    }
}

extern "C" void kernel_launch(void* const* d_in, const int* in_sizes, int n_in,
                              void* d_out, int out_size, void* d_ws, size_t ws_size,
                              hipStream_t stream)
{
    const float* hidden = (const float*)d_in[0];
    const float* weight = (const float*)d_in[1];
    float* out  = (float*)d_out;
    float* wsf  = (float*)d_ws;
    unsigned short* w2hi = (unsigned short*)(wsf + 2 * NB * NEXP);  // +4096 B
    unsigned short* w2lo = w2hi + NEXP * HDIM;

    hipMemsetAsync(d_ws, 0, 2 * NB * NEXP * sizeof(float), stream);
    wsplit<<<32, 256, 0, stream>>>(weight, w2hi, w2lo);
    moe_main<<<NBLK, NTHR, 0, stream>>>(hidden, w2hi, w2lo, out, wsf);
    moe_finalize<<<1, 64, 0, stream>>>(wsf, out);
}

// Round 4
// 219.372 us; speedup vs baseline: 1.8218x; 1.8218x over previous
//
#include <hip/hip_runtime.h>

#define NTOK 32768      // 8*4096 tokens
#define HDIM 1024
#define NEXP 64
#define TK   8
#define NB   8
#define SEQ  4096

#define MB   64         // tokens per block
#define KC   64         // K chunk (16 chunks)
#define NCH  (HDIM / KC)
#define NTHR 512        // 8 waves: wm=w>>1 tokens [16wm,+16), wn=w&1 experts [32wn,+32)

// per-chunk buffer layout inside smem: A 16KB | Bhi 8KB | Blo 8KB
#define BUFSZ   32768
#define BHI_OFF 16384
#define BLO_OFF 24576

typedef __attribute__((ext_vector_type(8))) short bf16x8;   // 8 bf16 = 4 VGPRs
typedef __attribute__((ext_vector_type(4))) float f32x4;

union BF8 { bf16x8 v; unsigned u[4]; };

__device__ inline unsigned f2bf(float x) {          // RTN-even fp32 -> bf16 bits
    unsigned u = __float_as_uint(x);
    return (u + 0x7FFFu + ((u >> 16) & 1u)) >> 16;
}

__device__ inline void split4(float4 v, unsigned* hp, unsigned* lp) {
    unsigned h0 = f2bf(v.x), h1 = f2bf(v.y), h2 = f2bf(v.z), h3 = f2bf(v.w);
    unsigned l0 = f2bf(v.x - __uint_as_float(h0 << 16));
    unsigned l1 = f2bf(v.y - __uint_as_float(h1 << 16));
    unsigned l2 = f2bf(v.z - __uint_as_float(h2 << 16));
    unsigned l3 = f2bf(v.w - __uint_as_float(h3 << 16));
    hp[0] = h0 | (h1 << 16); hp[1] = h2 | (h3 << 16);
    lp[0] = l0 | (l1 << 16); lp[1] = l2 | (l3 << 16);
}

// async global->LDS, 16B/lane; LDS dest = wave-uniform base + lane*16
__device__ __forceinline__ void gl16(const void* g, void* l) {
    __builtin_amdgcn_global_load_lds(
        (const __attribute__((address_space(1))) void*)g,
        (__attribute__((address_space(3))) void*)l, 16, 0, 0);
}

// One-time: split W into Dekker hi/lo bf16 AND pre-arrange in MFMA B-fragment
// order: slot(c,s,n) holds 64 lanes x 16B; lane l -> B[e=n*16+(l&15)]
// [k=c*64+s*32+(l>>4)*8 .. +8]. Slot-major layout => chunk c's fragments are a
// CONTIGUOUS 8KB run (hi) + 8KB (lo): stageable with gl16.
__global__ void wsplit(const float* __restrict__ w,
                       unsigned short* __restrict__ whi,
                       unsigned short* __restrict__ wlo)
{
    int T = blockIdx.x * 256 + threadIdx.x;     // 8192 threads = 128 slots x 64
    int slot = T >> 6, l = T & 63;
    int c = slot >> 3, s = (slot >> 2) & 1, n = slot & 3;
    int e = n * 16 + (l & 15);
    int k = c * 64 + s * 32 + (l >> 4) * 8;
    const float* src = w + (size_t)e * HDIM + k;
    float4 v0 = *(const float4*)(src);
    float4 v1 = *(const float4*)(src + 4);
    unsigned hp[4], lp[4];
    split4(v0, &hp[0], &lp[0]);
    split4(v1, &hp[2], &lp[2]);
    ((uint4*)whi)[T] = make_uint4(hp[0], hp[1], hp[2], hp[3]);
    ((uint4*)wlo)[T] = make_uint4(lp[0], lp[1], lp[2], lp[3]);
}

// R4 = R2 structure + per-block chunk ROTATION. R0-R2 all pinned at
// dur = FETCH/~780GB/s regardless of traffic volume: with lockstep K-chunking,
// every block reads column offset c*256B (mod 4KB) simultaneously -> identical
// low address bits chip-wide -> all requests hash to ~1/16 of the HBM
// channels / L3 slices (8TB/s / ~10 = the measured 780GB/s). Block b now
// processes chunks in order (c + b) & 15, so at any instant the 512 blocks
// cover all 16 column offsets -> full channel parallelism. K-accumulation
// order rotates per block: ~1ulp fp32 reorder, negligible vs bf16x3 error.
// R3's lesson kept: NO vmem loads between prefetch-issue and barrier (B reads
// are ds_read/lgkmcnt), so the prefetch queue never force-drains early.
__global__ __launch_bounds__(NTHR, 4) void moe_main(
    const float* __restrict__ hidden,           // [NTOK][HDIM]
    const unsigned short* __restrict__ w2hi,    // frag-ordered bf16 hi
    const unsigned short* __restrict__ w2lo,    // frag-ordered bf16 lo
    float* __restrict__ out,                    // idx | w | aux | counts
    float* __restrict__ ws)                     // C[8][64] | Sm[8][64]
{
    __shared__ __align__(16) unsigned char smem[2 * BUFSZ];  // dbuf 2x(A|Bhi|Blo)
    float* sLog = (float*)smem;                              // [64][66] alias
    __shared__ float mxArr[MB];
    __shared__ float smSum[NEXP];
    __shared__ int   hist[NEXP];

    const int tid   = threadIdx.x;
    const int w     = tid >> 6;         // 0..7
    const int l     = tid & 63;
    const int m     = l & 15;
    const int q     = l >> 4;
    const int wm    = w >> 1;           // token group: rows [16*wm, 16*wm+16)
    const int wn    = w & 1;            // expert group: cols [32*wn, 32*wn+32)
    const int t0    = blockIdx.x * MB;
    const int wbase = tid & 448;        // wave-uniform slot base (tid & ~63)
    const int c0    = blockIdx.x & 15;  // chunk rotation start (channel spread)

    if (tid < NEXP) { smSum[tid] = 0.f; hist[tid] = 0; }

    f32x4 acc[2];
#pragma unroll
    for (int n = 0; n < 2; ++n) acc[n] = (f32x4)0.f;

    // prologue: stage chunk c0 (A XOR-swizzled + B linear) into buf 0
#pragma unroll
    for (int i = 0; i < 2; ++i) {
        int slot = i * NTHR + tid;
        int r = slot >> 4, p = slot & 15, b = p ^ (r & 15);
        gl16(hidden + (size_t)(t0 + r) * HDIM + c0 * KC + b * 4,
             smem + (size_t)(i * NTHR + wbase) * 16);
    }
    gl16(w2hi + (size_t)c0 * 4096 + (size_t)tid * 8, smem + BHI_OFF + (size_t)wbase * 16);
    gl16(w2lo + (size_t)c0 * 4096 + (size_t)tid * 8, smem + BLO_OFF + (size_t)wbase * 16);
    __syncthreads();

    for (int c = 0; c < NCH; ++c) {
        const unsigned char* Ab = smem + (c & 1) * BUFSZ;

        // prefetch chunk cc+1 (A + B) into the other buffer; issued first so the
        // whole compute phase overlaps the in-flight loads (vmcnt(0) drain sits
        // at the end-of-chunk barrier). No vmem reads below this point.
        if (c + 1 < NCH) {
            unsigned char* nb = smem + ((c + 1) & 1) * BUFSZ;
            const int cc1 = (c + 1 + c0) & 15;
            const int kc = cc1 * KC;
#pragma unroll
            for (int i = 0; i < 2; ++i) {
                int slot = i * NTHR + tid;
                int r = slot >> 4, p = slot & 15, b = p ^ (r & 15);
                gl16(hidden + (size_t)(t0 + r) * HDIM + kc + b * 4,
                     nb + (size_t)(i * NTHR + wbase) * 16);
            }
            gl16(w2hi + (size_t)cc1 * 4096 + (size_t)tid * 8,
                 nb + BHI_OFF + (size_t)wbase * 16);
            gl16(w2lo + (size_t)cc1 * 4096 + (size_t)tid * 8,
                 nb + BLO_OFF + (size_t)wbase * 16);
        }

        // B fragments from LDS (contiguous 16B/lane within 1KB slots)
        bf16x8 bh[2][2], bl[2][2];
#pragma unroll
        for (int s = 0; s < 2; ++s)
#pragma unroll
            for (int n = 0; n < 2; ++n) {
                int off = ((s * 4 + wn * 2 + n) * 64 + l) * 16;
                bh[s][n] = *(const bf16x8*)(Ab + BHI_OFF + off);
                bl[s][n] = *(const bf16x8*)(Ab + BLO_OFF + off);
            }

        // compute chunk cc: 2 K32-steps, wave tile M=16 x N=32
#pragma unroll
        for (int s = 0; s < 2; ++s) {
            const int r  = wm * 16 + m;         // r & 15 == m
            const int b0 = s * 8 + q * 2;
            const int p0 = b0 ^ m, p1 = (b0 + 1) ^ m;
            float4 a0 = *(const float4*)(Ab + ((size_t)r * 16 + p0) * 16);
            float4 a1 = *(const float4*)(Ab + ((size_t)r * 16 + p1) * 16);
            BF8 ah, al;
            split4(a0, &ah.u[0], &al.u[0]);
            split4(a1, &ah.u[2], &al.u[2]);
#pragma unroll
            for (int n = 0; n < 2; ++n) {
                acc[n] = __builtin_amdgcn_mfma_f32_16x16x32_bf16(ah.v, bh[s][n], acc[n], 0, 0, 0);
                acc[n] = __builtin_amdgcn_mfma_f32_16x16x32_bf16(al.v, bh[s][n], acc[n], 0, 0, 0);
                acc[n] = __builtin_amdgcn_mfma_f32_16x16x32_bf16(ah.v, bl[s][n], acc[n], 0, 0, 0);
            }
        }
        __syncthreads();    // one barrier/chunk: (cc+1) staging drain overlapped
    }

    // epilogue: C/D layout row=(lane>>4)*4+reg (token), col=lane&15 (expert)
#pragma unroll
    for (int n = 0; n < 2; ++n)
#pragma unroll
        for (int r = 0; r < 4; ++r)
            sLog[(wm * 16 + q * 4 + r) * 66 + (wn * 2 + n) * 16 + m] = acc[n][r];
    __syncthreads();

    // ---- phase 2a: softmax stats (lane = expert); wave w: tokens [8w, 8w+8)
    float regSm = 0.f;
    for (int j = 0; j < 8; ++j) {
        int t = w * 8 + j;
        float x = sLog[t * 66 + l];
        float mx = x;
#pragma unroll
        for (int off = 32; off; off >>= 1) mx = fmaxf(mx, __shfl_xor(mx, off));
        float p = __expf(x - mx);
        float sd = p;
#pragma unroll
        for (int off = 32; off; off >>= 1) sd += __shfl_xor(sd, off);
        regSm += p / sd;
        if (l == 0) mxArr[t] = mx;
    }
    atomicAdd(&smSum[l], regSm);
    __syncthreads();

    // ---- phase 2b: top-8 per token, lane = token (wave 0 only) ----
    if (w == 0) {
        const float mx = mxArr[l];
        unsigned long long s8[TK];
#pragma unroll
        for (int j = 0; j < TK; ++j) s8[j] = 0ull;
        for (int e = 0; e < NEXP; ++e) {
            float x = sLog[l * 66 + e];
            unsigned u = __float_as_uint(x);
            unsigned k32 = (u & 0x80000000u) ? ~u : (u | 0x80000000u);
            unsigned long long key = ((unsigned long long)k32 << 6)
                                   | (unsigned long long)(63 - e);
            if (key > s8[TK - 1]) {
#pragma unroll
                for (int j = 0; j < TK; ++j) {
                    unsigned long long hi = s8[j] > key ? s8[j] : key;
                    key = s8[j] > key ? key : s8[j];
                    s8[j] = hi;
                }
            }
        }
        float ev[TK]; int ei[TK]; float sum = 0.f;
#pragma unroll
        for (int j = 0; j < TK; ++j) {
            unsigned k32 = (unsigned)(s8[j] >> 6);
            unsigned u = (k32 >> 31) ? (k32 ^ 0x80000000u) : ~k32;
            ev[j] = __expf(__uint_as_float(u) - mx);
            sum += ev[j];
            ei[j] = 63 - (int)(s8[j] & 63ull);
        }
        int t = t0 + l;
        float4 i0 = make_float4((float)ei[0], (float)ei[1], (float)ei[2], (float)ei[3]);
        float4 i1 = make_float4((float)ei[4], (float)ei[5], (float)ei[6], (float)ei[7]);
        *(float4*)(out + (size_t)t * TK)     = i0;
        *(float4*)(out + (size_t)t * TK + 4) = i1;
        float rs = 1.f / (sum + 1e-20f);
        float4 w0 = make_float4(ev[0] * rs, ev[1] * rs, ev[2] * rs, ev[3] * rs);
        float4 w1 = make_float4(ev[4] * rs, ev[5] * rs, ev[6] * rs, ev[7] * rs);
        *(float4*)(out + (size_t)NTOK * TK + (size_t)t * TK)     = w0;
        *(float4*)(out + (size_t)NTOK * TK + (size_t)t * TK + 4) = w1;
#pragma unroll
        for (int j = 0; j < TK; ++j) atomicAdd(&hist[ei[j]], 1);
    }
    __syncthreads();

    if (tid < NEXP) {
        int b = blockIdx.x >> 6;            // 64 blocks per batch element
        atomicAdd(&ws[b * NEXP + tid], (float)hist[tid]);
        atomicAdd(&ws[NB * NEXP + b * NEXP + tid], smSum[tid]);
    }
}

__global__ void moe_finalize(const float* __restrict__ ws, float* __restrict__ out)
{
    int e = threadIdx.x;   // 64 threads
    float cnt = 0.f, accv = 0.f;
#pragma unroll
    for (int b = 0; b < NB; ++b) {
        float c  = ws[b * NEXP + e];
        float sm = ws[NB * NEXP + b * NEXP + e];
        cnt += c;
        accv += c * sm;
    }
    out[(size_t)NTOK * TK * 2 + 1 + e] = cnt;   // expert_counts (as float)
#pragma unroll
    for (int off = 32; off; off >>= 1) accv += __shfl_xor(accv, off);
    if (e == 0) {
        float aux = 0.01f * accv * ((float)NEXP / ((float)SEQ * (float)TK))
                    / (float)SEQ / (float)NB;
        out[(size_t)NTOK * TK * 2] = aux;
    }
}

extern "C" void kernel_launch(void* const* d_in, const int* in_sizes, int n_in,
                              void* d_out, int out_size, void* d_ws, size_t ws_size,
                              hipStream_t stream)
{
    const float* hidden = (const float*)d_in[0];
    const float* weight = (const float*)d_in[1];
    float* out  = (float*)d_out;
    float* wsf  = (float*)d_ws;
    unsigned short* w2hi = (unsigned short*)(wsf + 2 * NB * NEXP);  // +4096 B
    unsigned short* w2lo = w2hi + NEXP * HDIM;

    hipMemsetAsync(d_ws, 0, 2 * NB * NEXP * sizeof(float), stream);
    wsplit<<<32, 256, 0, stream>>>(weight, w2hi, w2lo);
    moe_main<<<NTOK / MB, NTHR, 0, stream>>>(hidden, w2hi, w2lo, out, wsf);
    moe_finalize<<<1, 64, 0, stream>>>(wsf, out);
}

// Round 5
// 216.709 us; speedup vs baseline: 1.8442x; 1.0123x over previous
//
#include <hip/hip_runtime.h>

#define NTOK 32768      // 8*4096 tokens
#define HDIM 1024
#define NEXP 64
#define TK   8
#define NB   8
#define SEQ  4096

#define MB   64         // tokens per block
#define KC   64         // K chunk (16 chunks)
#define NCH  (HDIM / KC)
#define NTHR 512        // 8 waves: wm=w>>1 tokens [16wm,+16), wn=w&1 experts [32wn,+32)

// per-chunk buffer layout inside smem: A 16KB | Bhi 8KB | Blo 8KB
#define BUFSZ   32768
#define BHI_OFF 16384
#define BLO_OFF 24576

typedef __attribute__((ext_vector_type(8))) short bf16x8;   // 8 bf16 = 4 VGPRs
typedef __attribute__((ext_vector_type(4))) float f32x4;

union BF8 { bf16x8 v; unsigned u[4]; };

__device__ inline unsigned f2bf(float x) {          // RTN-even fp32 -> bf16 bits
    unsigned u = __float_as_uint(x);
    return (u + 0x7FFFu + ((u >> 16) & 1u)) >> 16;
}

__device__ inline void split4(float4 v, unsigned* hp, unsigned* lp) {
    unsigned h0 = f2bf(v.x), h1 = f2bf(v.y), h2 = f2bf(v.z), h3 = f2bf(v.w);
    unsigned l0 = f2bf(v.x - __uint_as_float(h0 << 16));
    unsigned l1 = f2bf(v.y - __uint_as_float(h1 << 16));
    unsigned l2 = f2bf(v.z - __uint_as_float(h2 << 16));
    unsigned l3 = f2bf(v.w - __uint_as_float(h3 << 16));
    hp[0] = h0 | (h1 << 16); hp[1] = h2 | (h3 << 16);
    lp[0] = l0 | (l1 << 16); lp[1] = l2 | (l3 << 16);
}

// async global->LDS, 16B/lane; LDS dest = wave-uniform base + lane*16
__device__ __forceinline__ void gl16(const void* g, void* l) {
    __builtin_amdgcn_global_load_lds(
        (const __attribute__((address_space(1))) void*)g,
        (__attribute__((address_space(3))) void*)l, 16, 0, 0);
}

// One-time: split W into Dekker hi/lo bf16 AND pre-arrange in MFMA B-fragment
// order: slot(c,s,n) holds 64 lanes x 16B; lane l -> B[e=n*16+(l&15)]
// [k=c*64+s*32+(l>>4)*8 .. +8]. Slot-major layout => chunk c's fragments are a
// CONTIGUOUS 8KB run (hi) + 8KB (lo): stageable with gl16.
__global__ void wsplit(const float* __restrict__ w,
                       unsigned short* __restrict__ whi,
                       unsigned short* __restrict__ wlo)
{
    int T = blockIdx.x * 256 + threadIdx.x;     // 8192 threads = 128 slots x 64
    int slot = T >> 6, l = T & 63;
    int c = slot >> 3, s = (slot >> 2) & 1, n = slot & 3;
    int e = n * 16 + (l & 15);
    int k = c * 64 + s * 32 + (l >> 4) * 8;
    const float* src = w + (size_t)e * HDIM + k;
    float4 v0 = *(const float4*)(src);
    float4 v1 = *(const float4*)(src + 4);
    unsigned hp[4], lp[4];
    split4(v0, &hp[0], &lp[0]);
    split4(v1, &hp[2], &lp[2]);
    ((uint4*)whi)[T] = make_uint4(hp[0], hp[1], hp[2], hp[3]);
    ((uint4*)wlo)[T] = make_uint4(lp[0], lp[1], lp[2], lp[3]);
}

// R5 = R4 with the loop body REORDERED: all LDS reads of chunk c (B frags +
// raw A float4s) are issued BEFORE the gl16 prefetch of chunk c+1.
// Why: global_load_lds is an async LDS write tracked by vmcnt; hipcc cannot
// prove the ds_reads (same smem array, dynamic offsets) don't alias the
// in-flight gl16 writes, so with prefetch-first ordering it must emit
// s_waitcnt vmcnt(0) BEFORE the first ds_read -> the entire prefetch drains
// at the top of compute -> zero overlap. That serial staging round-trip
// (~16MB/chunk chip-wide at ~3TB/s ~= 5.2us x 16 = 83us) is exactly the
// measured R2/R4 time, and explains why occupancy (R1), traffic volume (R2),
// and channel rotation (R4) were all ~neutral. With reads-first, the only
// vmcnt(0) sits at the end-of-chunk barrier, after a full compute phase.
__global__ __launch_bounds__(NTHR, 4) void moe_main(
    const float* __restrict__ hidden,           // [NTOK][HDIM]
    const unsigned short* __restrict__ w2hi,    // frag-ordered bf16 hi
    const unsigned short* __restrict__ w2lo,    // frag-ordered bf16 lo
    float* __restrict__ out,                    // idx | w | aux | counts
    float* __restrict__ ws)                     // C[8][64] | Sm[8][64]
{
    __shared__ __align__(16) unsigned char smem[2 * BUFSZ];  // dbuf 2x(A|Bhi|Blo)
    float* sLog = (float*)smem;                              // [64][66] alias
    __shared__ float mxArr[MB];
    __shared__ float smSum[NEXP];
    __shared__ int   hist[NEXP];

    const int tid   = threadIdx.x;
    const int w     = tid >> 6;         // 0..7
    const int l     = tid & 63;
    const int m     = l & 15;
    const int q     = l >> 4;
    const int wm    = w >> 1;           // token group: rows [16*wm, 16*wm+16)
    const int wn    = w & 1;            // expert group: cols [32*wn, 32*wn+32)
    const int t0    = blockIdx.x * MB;
    const int wbase = tid & 448;        // wave-uniform slot base (tid & ~63)
    const int c0    = blockIdx.x & 15;  // chunk rotation start (channel spread)

    if (tid < NEXP) { smSum[tid] = 0.f; hist[tid] = 0; }

    f32x4 acc[2];
#pragma unroll
    for (int n = 0; n < 2; ++n) acc[n] = (f32x4)0.f;

    // prologue: stage chunk c0 (A XOR-swizzled + B linear) into buf 0
#pragma unroll
    for (int i = 0; i < 2; ++i) {
        int slot = i * NTHR + tid;
        int r = slot >> 4, p = slot & 15, b = p ^ (r & 15);
        gl16(hidden + (size_t)(t0 + r) * HDIM + c0 * KC + b * 4,
             smem + (size_t)(i * NTHR + wbase) * 16);
    }
    gl16(w2hi + (size_t)c0 * 4096 + (size_t)tid * 8, smem + BHI_OFF + (size_t)wbase * 16);
    gl16(w2lo + (size_t)c0 * 4096 + (size_t)tid * 8, smem + BLO_OFF + (size_t)wbase * 16);
    __syncthreads();

    for (int c = 0; c < NCH; ++c) {
        const unsigned char* Ab = smem + (c & 1) * BUFSZ;

        // (1) ALL LDS reads of chunk c first: B fragments into registers...
        bf16x8 bh[2][2], bl[2][2];
#pragma unroll
        for (int s = 0; s < 2; ++s)
#pragma unroll
            for (int n = 0; n < 2; ++n) {
                int off = ((s * 4 + wn * 2 + n) * 64 + l) * 16;
                bh[s][n] = *(const bf16x8*)(Ab + BHI_OFF + off);
                bl[s][n] = *(const bf16x8*)(Ab + BLO_OFF + off);
            }
        // ...and raw A float4s for both K32-steps
        float4 a0[2], a1[2];
#pragma unroll
        for (int s = 0; s < 2; ++s) {
            const int r  = wm * 16 + m;         // r & 15 == m
            const int b0 = s * 8 + q * 2;
            const int p0 = b0 ^ m, p1 = (b0 + 1) ^ m;
            a0[s] = *(const float4*)(Ab + ((size_t)r * 16 + p0) * 16);
            a1[s] = *(const float4*)(Ab + ((size_t)r * 16 + p1) * 16);
        }

        // (2) NOW issue the prefetch for chunk c+1 (other buffer). It stays in
        // flight through the whole compute phase; the vmcnt(0) drain sits at
        // the end-of-chunk barrier. No vmem/LDS reads below this point.
        if (c + 1 < NCH) {
            unsigned char* nb = smem + ((c + 1) & 1) * BUFSZ;
            const int cc1 = (c + 1 + c0) & 15;
            const int kc = cc1 * KC;
#pragma unroll
            for (int i = 0; i < 2; ++i) {
                int slot = i * NTHR + tid;
                int r = slot >> 4, p = slot & 15, b = p ^ (r & 15);
                gl16(hidden + (size_t)(t0 + r) * HDIM + kc + b * 4,
                     nb + (size_t)(i * NTHR + wbase) * 16);
            }
            gl16(w2hi + (size_t)cc1 * 4096 + (size_t)tid * 8,
                 nb + BHI_OFF + (size_t)wbase * 16);
            gl16(w2lo + (size_t)cc1 * 4096 + (size_t)tid * 8,
                 nb + BLO_OFF + (size_t)wbase * 16);
        }

        // (3) compute chunk c: 2 K32-steps, wave tile M=16 x N=32
#pragma unroll
        for (int s = 0; s < 2; ++s) {
            BF8 ah, al;
            split4(a0[s], &ah.u[0], &al.u[0]);
            split4(a1[s], &ah.u[2], &al.u[2]);
#pragma unroll
            for (int n = 0; n < 2; ++n) {
                acc[n] = __builtin_amdgcn_mfma_f32_16x16x32_bf16(ah.v, bh[s][n], acc[n], 0, 0, 0);
                acc[n] = __builtin_amdgcn_mfma_f32_16x16x32_bf16(al.v, bh[s][n], acc[n], 0, 0, 0);
                acc[n] = __builtin_amdgcn_mfma_f32_16x16x32_bf16(ah.v, bl[s][n], acc[n], 0, 0, 0);
            }
        }
        __syncthreads();    // (4) one barrier/chunk: prefetch drain overlapped
    }

    // epilogue: C/D layout row=(lane>>4)*4+reg (token), col=lane&15 (expert)
#pragma unroll
    for (int n = 0; n < 2; ++n)
#pragma unroll
        for (int r = 0; r < 4; ++r)
            sLog[(wm * 16 + q * 4 + r) * 66 + (wn * 2 + n) * 16 + m] = acc[n][r];
    __syncthreads();

    // ---- phase 2a: softmax stats (lane = expert); wave w: tokens [8w, 8w+8)
    float regSm = 0.f;
    for (int j = 0; j < 8; ++j) {
        int t = w * 8 + j;
        float x = sLog[t * 66 + l];
        float mx = x;
#pragma unroll
        for (int off = 32; off; off >>= 1) mx = fmaxf(mx, __shfl_xor(mx, off));
        float p = __expf(x - mx);
        float sd = p;
#pragma unroll
        for (int off = 32; off; off >>= 1) sd += __shfl_xor(sd, off);
        regSm += p / sd;
        if (l == 0) mxArr[t] = mx;
    }
    atomicAdd(&smSum[l], regSm);
    __syncthreads();

    // ---- phase 2b: top-8 per token, lane = token (wave 0 only) ----
    if (w == 0) {
        const float mx = mxArr[l];
        unsigned long long s8[TK];
#pragma unroll
        for (int j = 0; j < TK; ++j) s8[j] = 0ull;
        for (int e = 0; e < NEXP; ++e) {
            float x = sLog[l * 66 + e];
            unsigned u = __float_as_uint(x);
            unsigned k32 = (u & 0x80000000u) ? ~u : (u | 0x80000000u);
            unsigned long long key = ((unsigned long long)k32 << 6)
                                   | (unsigned long long)(63 - e);
            if (key > s8[TK - 1]) {
#pragma unroll
                for (int j = 0; j < TK; ++j) {
                    unsigned long long hi = s8[j] > key ? s8[j] : key;
                    key = s8[j] > key ? key : s8[j];
                    s8[j] = hi;
                }
            }
        }
        float ev[TK]; int ei[TK]; float sum = 0.f;
#pragma unroll
        for (int j = 0; j < TK; ++j) {
            unsigned k32 = (unsigned)(s8[j] >> 6);
            unsigned u = (k32 >> 31) ? (k32 ^ 0x80000000u) : ~k32;
            ev[j] = __expf(__uint_as_float(u) - mx);
            sum += ev[j];
            ei[j] = 63 - (int)(s8[j] & 63ull);
        }
        int t = t0 + l;
        float4 i0 = make_float4((float)ei[0], (float)ei[1], (float)ei[2], (float)ei[3]);
        float4 i1 = make_float4((float)ei[4], (float)ei[5], (float)ei[6], (float)ei[7]);
        *(float4*)(out + (size_t)t * TK)     = i0;
        *(float4*)(out + (size_t)t * TK + 4) = i1;
        float rs = 1.f / (sum + 1e-20f);
        float4 w0 = make_float4(ev[0] * rs, ev[1] * rs, ev[2] * rs, ev[3] * rs);
        float4 w1 = make_float4(ev[4] * rs, ev[5] * rs, ev[6] * rs, ev[7] * rs);
        *(float4*)(out + (size_t)NTOK * TK + (size_t)t * TK)     = w0;
        *(float4*)(out + (size_t)NTOK * TK + (size_t)t * TK + 4) = w1;
#pragma unroll
        for (int j = 0; j < TK; ++j) atomicAdd(&hist[ei[j]], 1);
    }
    __syncthreads();

    if (tid < NEXP) {
        int b = blockIdx.x >> 6;            // 64 blocks per batch element
        atomicAdd(&ws[b * NEXP + tid], (float)hist[tid]);
        atomicAdd(&ws[NB * NEXP + b * NEXP + tid], smSum[tid]);
    }
}

__global__ void moe_finalize(const float* __restrict__ ws, float* __restrict__ out)
{
    int e = threadIdx.x;   // 64 threads
    float cnt = 0.f, accv = 0.f;
#pragma unroll
    for (int b = 0; b < NB; ++b) {
        float c  = ws[b * NEXP + e];
        float sm = ws[NB * NEXP + b * NEXP + e];
        cnt += c;
        accv += c * sm;
    }
    out[(size_t)NTOK * TK * 2 + 1 + e] = cnt;   // expert_counts (as float)
#pragma unroll
    for (int off = 32; off; off >>= 1) accv += __shfl_xor(accv, off);
    if (e == 0) {
        float aux = 0.01f * accv * ((float)NEXP / ((float)SEQ * (float)TK))
                    / (float)SEQ / (float)NB;
        out[(size_t)NTOK * TK * 2] = aux;
    }
}

extern "C" void kernel_launch(void* const* d_in, const int* in_sizes, int n_in,
                              void* d_out, int out_size, void* d_ws, size_t ws_size,
                              hipStream_t stream)
{
    const float* hidden = (const float*)d_in[0];
    const float* weight = (const float*)d_in[1];
    float* out  = (float*)d_out;
    float* wsf  = (float*)d_ws;
    unsigned short* w2hi = (unsigned short*)(wsf + 2 * NB * NEXP);  // +4096 B
    unsigned short* w2lo = w2hi + NEXP * HDIM;

    hipMemsetAsync(d_ws, 0, 2 * NB * NEXP * sizeof(float), stream);
    wsplit<<<32, 256, 0, stream>>>(weight, w2hi, w2lo);
    moe_main<<<NTOK / MB, NTHR, 0, stream>>>(hidden, w2hi, w2lo, out, wsf);
    moe_finalize<<<1, 64, 0, stream>>>(wsf, out);
}